// Round 6
// baseline (178.503 us; speedup 1.0000x reference)
//
#include <hip/hip_runtime.h>

typedef unsigned int u32;
typedef unsigned short u16;
typedef __attribute__((ext_vector_type(4))) float f32x4;
typedef __attribute__((ext_vector_type(8))) __bf16 bf16x8;
typedef __attribute__((ext_vector_type(4))) u32 u32x4;

// fp32 -> bf16 round-to-nearest-even
__device__ __forceinline__ u32 f2bf(float f) {
    u32 u = __builtin_bit_cast(u32, f);
    return (u + 0x7fffu + ((u >> 16) & 1u)) >> 16;
}
// fp32 -> bf16 round-half-up (cheaper; only on hidden activations)
__device__ __forceinline__ u32 f2bf_fast(float f) {
    u32 u = __builtin_bit_cast(u32, f);
    return (u + 0x8000u) >> 16;
}
__device__ __forceinline__ u32 pk2(float lo, float hi) {
    return f2bf(lo) | (f2bf(hi) << 16);
}
// unpack bf16 pair from u32 (do NOT use __bf16 vector arithmetic on gfx950 —
// R4 showed it miscompiles; unpack to f32 explicitly)
__device__ __forceinline__ float bflo(u32 a) { return __builtin_bit_cast(float, a << 16); }
__device__ __forceinline__ float bfhi(u32 a) { return __builtin_bit_cast(float, a & 0xffff0000u); }

// 16 rows x 136 bf16 (+8 pad: 2-way-max bank aliasing = free per m136)
union LdsTile {
    u16 h[16 * 136];
    u32x4 v[16 * 17];
};

// ---------------------------------------------------------------------------
// Precompute kernel (unchanged from R5). relu comes AFTER the edge sum, so
// layer 1 factors per-node:  hidden = relu(np[src] + ap[dst])
// ---------------------------------------------------------------------------
__global__ __launch_bounds__(256, 2)
void precompute_kernel(const float* __restrict__ x_nbr,
                       const float* __restrict__ x_agent,
                       const float* __restrict__ W1,
                       const float* __restrict__ b1,
                       const float* __restrict__ Wa,
                       const float* __restrict__ ba,
                       u16* __restrict__ np, u16* __restrict__ ap,
                       float* __restrict__ out,
                       int n_nodes, int n_agents, int nbr_blocks)
{
    __shared__ LdsTile Abuf[4];
    const int wid = threadIdx.x >> 6;
    const int l   = threadIdx.x & 63;
    const int n   = l & 15;
    const int q   = l >> 4;
    const bool is_nbr = (int)blockIdx.x < nbr_blocks;

    const float* Wb = W1 + (is_nbr ? 0 : 128 * 128);
    u32x4 wf[8][4];
#pragma unroll
    for (int nt = 0; nt < 8; ++nt) {
        const int col = nt * 16 + n;
#pragma unroll
        for (int kk = 0; kk < 4; ++kk) {
            u32x4 w;
#pragma unroll
            for (int jp = 0; jp < 4; ++jp) {
                const int k = kk * 32 + q * 8 + jp * 2;
                w[jp] = pk2(Wb[(size_t)k * 128 + col], Wb[(size_t)(k + 1) * 128 + col]);
            }
            wf[nt][kk] = w;
        }
    }
    const f32x4 zero = {0.f, 0.f, 0.f, 0.f};

    if (is_nbr) {
        const int n_tiles = n_nodes >> 4;
        const int gw = blockIdx.x * 4 + wid;
        const int stride = nbr_blocks * 4;
        for (int t = gw; t < n_tiles; t += stride) {
            const int a0 = t * 16;
#pragma unroll
            for (int it = 0; it < 4; ++it) {
                const int m = it * 4 + q;
                const float* bp = x_nbr + (size_t)(a0 + m) * 128 + n * 8;
                const float4 v0 = *(const float4*)bp;
                const float4 v1 = *(const float4*)(bp + 4);
                u32x4 pkv;
                pkv[0] = pk2(v0.x, v0.y); pkv[1] = pk2(v0.z, v0.w);
                pkv[2] = pk2(v1.x, v1.y); pkv[3] = pk2(v1.z, v1.w);
                Abuf[wid].v[m * 17 + n] = pkv;
            }
            f32x4 acc[8];
#pragma unroll
            for (int nt = 0; nt < 8; ++nt) acc[nt] = zero;
#pragma unroll
            for (int kk = 0; kk < 4; ++kk) {
                const u32x4 a = Abuf[wid].v[n * 17 + kk * 4 + q];
#pragma unroll
                for (int nt = 0; nt < 8; ++nt)
                    acc[nt] = __builtin_amdgcn_mfma_f32_16x16x32_bf16(
                        __builtin_bit_cast(bf16x8, a),
                        __builtin_bit_cast(bf16x8, wf[nt][kk]), acc[nt], 0, 0, 0);
            }
#pragma unroll
            for (int nt = 0; nt < 8; ++nt)
#pragma unroll
                for (int r = 0; r < 4; ++r)
                    np[(size_t)(a0 + q * 4 + r) * 128 + nt * 16 + n] =
                        (u16)f2bf(acc[nt][r]);
        }
    } else {
        u32x4 waf[4];
#pragma unroll
        for (int kk = 0; kk < 4; ++kk) {
            u32x4 w;
#pragma unroll
            for (int jp = 0; jp < 4; ++jp) {
                const int k = kk * 32 + q * 8 + jp * 2;
                const float f0 = (n < 8) ? Wa[(size_t)k * 8 + n] : 0.f;
                const float f1 = (n < 8) ? Wa[(size_t)(k + 1) * 8 + n] : 0.f;
                w[jp] = pk2(f0, f1);
            }
            waf[kk] = w;
        }
        float b1v[8];
#pragma unroll
        for (int nt = 0; nt < 8; ++nt) b1v[nt] = b1[nt * 16 + n];
        const float bav = (n < 8) ? ba[n] : 0.f;

        const int n_tiles = n_agents >> 4;
        const int agent_blocks = gridDim.x - nbr_blocks;
        const int gw = (blockIdx.x - nbr_blocks) * 4 + wid;
        const int stride = agent_blocks * 4;
        for (int t = gw; t < n_tiles; t += stride) {
            const int a0 = t * 16;
#pragma unroll
            for (int it = 0; it < 4; ++it) {
                const int m = it * 4 + q;
                const float* bp = x_agent + (size_t)(a0 + m) * 128 + n * 8;
                const float4 v0 = *(const float4*)bp;
                const float4 v1 = *(const float4*)(bp + 4);
                u32x4 pkv;
                pkv[0] = pk2(v0.x, v0.y); pkv[1] = pk2(v0.z, v0.w);
                pkv[2] = pk2(v1.x, v1.y); pkv[3] = pk2(v1.z, v1.w);
                Abuf[wid].v[m * 17 + n] = pkv;
            }
            f32x4 acc[8];
#pragma unroll
            for (int nt = 0; nt < 8; ++nt) acc[nt] = zero;
            f32x4 acca = zero;
#pragma unroll
            for (int kk = 0; kk < 4; ++kk) {
                const u32x4 a = Abuf[wid].v[n * 17 + kk * 4 + q];
#pragma unroll
                for (int nt = 0; nt < 8; ++nt)
                    acc[nt] = __builtin_amdgcn_mfma_f32_16x16x32_bf16(
                        __builtin_bit_cast(bf16x8, a),
                        __builtin_bit_cast(bf16x8, wf[nt][kk]), acc[nt], 0, 0, 0);
                acca = __builtin_amdgcn_mfma_f32_16x16x32_bf16(
                    __builtin_bit_cast(bf16x8, a),
                    __builtin_bit_cast(bf16x8, waf[kk]), acca, 0, 0, 0);
            }
#pragma unroll
            for (int nt = 0; nt < 8; ++nt)
#pragma unroll
                for (int r = 0; r < 4; ++r)
                    ap[(size_t)(a0 + q * 4 + r) * 128 + nt * 16 + n] =
                        (u16)f2bf(acc[nt][r] + b1v[nt]);
            const float4 z = {0.f, 0.f, 0.f, 0.f};
#pragma unroll
            for (int it = 0; it < 4; ++it) {
                const int m = it * 4 + q;
                float4* zp = (float4*)(out + (size_t)(a0 + m) * 264 + 128 + n * 8);
                zp[0] = z; zp[1] = z;
            }
#pragma unroll
            for (int r = 0; r < 4; ++r) {
                const int m = q * 4 + r;
                if (n < 8) out[(size_t)(a0 + m) * 264 + 256 + n] = acca[r] + bav;
            }
        }
    }
}

// ---------------------------------------------------------------------------
// Edge kernel, depth-2 software pipeline: while computing tile t, gathers for
// t+S and t+2S are both in flight (3 rotating fragment sets), doubling
// per-wave outstanding misses vs R5's ping-pong. Little's law: achieved
// request BW == in-flight*64B/latency, so 2x in-flight -> ~2x throughput if
// latency-bound. No LDS, no barriers.
// ---------------------------------------------------------------------------
#define EDGE_STEP(C, M, F)                                                       \
  {                                                                              \
    const int t3 = (t2 + stride < n_tiles) ? t2 + stride : t2;                   \
    /* issue gathers for tile t2 into set F (idx loaded last step) */            \
    const int sF = __shfl(src##F, n);                                            \
    _Pragma("unroll") for (int kk = 0; kk < 4; ++kk)                             \
        npf##F[kk] = *(const u32x4*)(np + (size_t)sF * 128 + kk * 32 + q * 8);   \
    _Pragma("unroll") for (int kk = 0; kk < 4; ++kk)                             \
        apf##F[kk] = *(const u32x4*)(ap + (size_t)dst##F * 128 + kk * 32 + q * 8);\
    const int sslot = slot##C;                                                   \
    const int sdst  = dst##C;                                                    \
    const bool done = (t1 == t);                                                 \
    if (!done) {                                                                 \
        if (l < 16) { src##C = edge_src[t3 * 16 + l];                            \
                      slot##C = edge_slot[t3 * 16 + l]; }                        \
        dst##C = edge_dst[t3 * 16];                                              \
    }                                                                            \
    /* compute tile t from set C (loads issued 2 steps ago) */                   \
    f32x4 acc2 = {0.f, 0.f, 0.f, 0.f};                                           \
    _Pragma("unroll") for (int kk = 0; kk < 4; ++kk) {                           \
        u32x4 hf;                                                                \
        _Pragma("unroll") for (int j = 0; j < 4; ++j) {                          \
            const u32 av = npf##C[kk][j], bv = apf##C[kk][j];                    \
            const float lo = fmaxf(bflo(av) + bflo(bv), 0.f);                    \
            const float hi = fmaxf(bfhi(av) + bfhi(bv), 0.f);                    \
            hf[j] = f2bf_fast(lo) | (f2bf_fast(hi) << 16);                       \
        }                                                                        \
        acc2 = __builtin_amdgcn_mfma_f32_16x16x32_bf16(                          \
            __builtin_bit_cast(bf16x8, hf),                                      \
            __builtin_bit_cast(bf16x8, w2f[kk]), acc2, 0, 0, 0);                 \
    }                                                                            \
    float* orow = out + (size_t)sdst * 264;                                      \
    _Pragma("unroll") for (int r = 0; r < 4; ++r) {                              \
        const int sl = __shfl(sslot, q * 4 + r);                                 \
        if (n < 8) orow[sl * 8 + n] = acc2[r] + b2v;                             \
    }                                                                            \
    if (done) break;                                                             \
    t = t1; t1 = t2; t2 = t3;                                                    \
  }

__global__ __launch_bounds__(256, 3)
void edge_kernel(const u16* __restrict__ np, const u16* __restrict__ ap,
                 const float* __restrict__ W2, const float* __restrict__ b2,
                 const int* __restrict__ edge_src,
                 const int* __restrict__ edge_dst,
                 const int* __restrict__ edge_slot,
                 float* __restrict__ out, int n_tiles)
{
    const int wid = threadIdx.x >> 6;
    const int l   = threadIdx.x & 63;
    const int n   = l & 15;
    const int q   = l >> 4;

    // W2 B-fragments (N padded 8->16 with zeros): 16 VGPRs
    u32x4 w2f[4];
#pragma unroll
    for (int kk = 0; kk < 4; ++kk) {
        u32x4 w;
#pragma unroll
        for (int jp = 0; jp < 4; ++jp) {
            const int k = kk * 32 + q * 8 + jp * 2;
            const float f0 = (n < 8) ? W2[(size_t)k * 8 + n] : 0.f;
            const float f1 = (n < 8) ? W2[(size_t)(k + 1) * 8 + n] : 0.f;
            w[jp] = pk2(f0, f1);
        }
        w2f[kk] = w;
    }
    const float b2v = (n < 8) ? b2[n] : 0.f;

    const int stride = gridDim.x * 4;
    int t = blockIdx.x * 4 + wid;
    if (t >= n_tiles) return;
    int t1 = (t + stride < n_tiles) ? t + stride : t;
    int t2 = (t1 + stride < n_tiles) ? t1 + stride : t1;

    // idx for tiles t, t1, t2
    int src0 = 0, slot0 = 0, src1 = 0, slot1 = 0, src2 = 0, slot2 = 0;
    if (l < 16) {
        src0 = edge_src[t  * 16 + l]; slot0 = edge_slot[t  * 16 + l];
        src1 = edge_src[t1 * 16 + l]; slot1 = edge_slot[t1 * 16 + l];
        src2 = edge_src[t2 * 16 + l]; slot2 = edge_slot[t2 * 16 + l];
    }
    int dst0 = edge_dst[t * 16];
    int dst1 = edge_dst[t1 * 16];
    int dst2 = edge_dst[t2 * 16];

    // pre-issue gathers for tiles t (set 0) and t1 (set 1)
    u32x4 npf0[4], apf0[4], npf1[4], apf1[4], npf2[4], apf2[4];
    {
        const int s0 = __shfl(src0, n);
#pragma unroll
        for (int kk = 0; kk < 4; ++kk)
            npf0[kk] = *(const u32x4*)(np + (size_t)s0 * 128 + kk * 32 + q * 8);
#pragma unroll
        for (int kk = 0; kk < 4; ++kk)
            apf0[kk] = *(const u32x4*)(ap + (size_t)dst0 * 128 + kk * 32 + q * 8);
        const int s1 = __shfl(src1, n);
#pragma unroll
        for (int kk = 0; kk < 4; ++kk)
            npf1[kk] = *(const u32x4*)(np + (size_t)s1 * 128 + kk * 32 + q * 8);
#pragma unroll
        for (int kk = 0; kk < 4; ++kk)
            apf1[kk] = *(const u32x4*)(ap + (size_t)dst1 * 128 + kk * 32 + q * 8);
    }

    while (true) {
        EDGE_STEP(0, 1, 2)
        EDGE_STEP(1, 2, 0)
        EDGE_STEP(2, 0, 1)
    }
}

extern "C" void kernel_launch(void* const* d_in, const int* in_sizes, int n_in,
                              void* d_out, int out_size, void* d_ws, size_t ws_size,
                              hipStream_t stream)
{
    const float* x_nbr   = (const float*)d_in[0];
    const float* x_agent = (const float*)d_in[1];
    const float* W1      = (const float*)d_in[2];
    const float* b1      = (const float*)d_in[3];
    const float* W2      = (const float*)d_in[4];
    const float* b2      = (const float*)d_in[5];
    const float* Wa      = (const float*)d_in[6];
    const float* ba      = (const float*)d_in[7];
    const int* edge_src  = (const int*)d_in[8];
    const int* edge_dst  = (const int*)d_in[9];
    const int* edge_slot = (const int*)d_in[10];

    const int E        = in_sizes[8];
    const int n_nodes  = in_sizes[0] / 128;
    const int n_agents = in_sizes[1] / 128;
    const int n_tiles  = E / 16;

    // ws: np (n_nodes*128 bf16 = 12.8 MB) | ap (n_agents*128 bf16 = 12.8 MB)
    u16* np = (u16*)d_ws;
    u16* ap = (u16*)d_ws + (size_t)n_nodes * 128;

    const int nbr_blocks = 512, agent_blocks = 512;
    precompute_kernel<<<dim3(nbr_blocks + agent_blocks), dim3(256), 0, stream>>>(
        x_nbr, x_agent, W1, b1, Wa, ba, np, ap, (float*)d_out,
        n_nodes, n_agents, nbr_blocks);
    // 768 blocks = 3 blocks/CU exactly at launch_bounds(256,3)
    edge_kernel<<<dim3(768), dim3(256), 0, stream>>>(
        np, ap, W2, b2, edge_src, edge_dst, edge_slot, (float*)d_out, n_tiles);
}

// Round 7
// 174.309 us; speedup vs baseline: 1.0241x; 1.0241x over previous
//
#include <hip/hip_runtime.h>

typedef unsigned int u32;
typedef unsigned short u16;
typedef __attribute__((ext_vector_type(4))) float f32x4;
typedef __attribute__((ext_vector_type(8))) __bf16 bf16x8;
typedef __attribute__((ext_vector_type(4))) u32 u32x4;

// fp32 -> bf16 round-to-nearest-even
__device__ __forceinline__ u32 f2bf(float f) {
    u32 u = __builtin_bit_cast(u32, f);
    return (u + 0x7fffu + ((u >> 16) & 1u)) >> 16;
}
// fp32 -> bf16 round-half-up (cheaper; only on hidden activations)
__device__ __forceinline__ u32 f2bf_fast(float f) {
    u32 u = __builtin_bit_cast(u32, f);
    return (u + 0x8000u) >> 16;
}
__device__ __forceinline__ u32 pk2(float lo, float hi) {
    return f2bf(lo) | (f2bf(hi) << 16);
}
// unpack bf16 pair from u32 (do NOT use __bf16 vector arithmetic on gfx950 —
// R4 showed it miscompiles; unpack to f32 explicitly)
__device__ __forceinline__ float bflo(u32 a) { return __builtin_bit_cast(float, a << 16); }
__device__ __forceinline__ float bfhi(u32 a) { return __builtin_bit_cast(float, a & 0xffff0000u); }

union LdsTile {
    u16 h[16 * 136];
    u32x4 v[16 * 17];
};

// ---------------------------------------------------------------------------
// Precompute kernel (unchanged from R5/R6 — passed).
// ---------------------------------------------------------------------------
__global__ __launch_bounds__(256, 2)
void precompute_kernel(const float* __restrict__ x_nbr,
                       const float* __restrict__ x_agent,
                       const float* __restrict__ W1,
                       const float* __restrict__ b1,
                       const float* __restrict__ Wa,
                       const float* __restrict__ ba,
                       u16* __restrict__ np, u16* __restrict__ ap,
                       float* __restrict__ out,
                       int n_nodes, int n_agents, int nbr_blocks)
{
    __shared__ LdsTile Abuf[4];
    const int wid = threadIdx.x >> 6;
    const int l   = threadIdx.x & 63;
    const int n   = l & 15;
    const int q   = l >> 4;
    const bool is_nbr = (int)blockIdx.x < nbr_blocks;

    const float* Wb = W1 + (is_nbr ? 0 : 128 * 128);
    u32x4 wf[8][4];
#pragma unroll
    for (int nt = 0; nt < 8; ++nt) {
        const int col = nt * 16 + n;
#pragma unroll
        for (int kk = 0; kk < 4; ++kk) {
            u32x4 w;
#pragma unroll
            for (int jp = 0; jp < 4; ++jp) {
                const int k = kk * 32 + q * 8 + jp * 2;
                w[jp] = pk2(Wb[(size_t)k * 128 + col], Wb[(size_t)(k + 1) * 128 + col]);
            }
            wf[nt][kk] = w;
        }
    }
    const f32x4 zero = {0.f, 0.f, 0.f, 0.f};

    if (is_nbr) {
        const int n_tiles = n_nodes >> 4;
        const int gw = blockIdx.x * 4 + wid;
        const int stride = nbr_blocks * 4;
        for (int t = gw; t < n_tiles; t += stride) {
            const int a0 = t * 16;
#pragma unroll
            for (int it = 0; it < 4; ++it) {
                const int m = it * 4 + q;
                const float* bp = x_nbr + (size_t)(a0 + m) * 128 + n * 8;
                const float4 v0 = *(const float4*)bp;
                const float4 v1 = *(const float4*)(bp + 4);
                u32x4 pkv;
                pkv[0] = pk2(v0.x, v0.y); pkv[1] = pk2(v0.z, v0.w);
                pkv[2] = pk2(v1.x, v1.y); pkv[3] = pk2(v1.z, v1.w);
                Abuf[wid].v[m * 17 + n] = pkv;
            }
            f32x4 acc[8];
#pragma unroll
            for (int nt = 0; nt < 8; ++nt) acc[nt] = zero;
#pragma unroll
            for (int kk = 0; kk < 4; ++kk) {
                const u32x4 a = Abuf[wid].v[n * 17 + kk * 4 + q];
#pragma unroll
                for (int nt = 0; nt < 8; ++nt)
                    acc[nt] = __builtin_amdgcn_mfma_f32_16x16x32_bf16(
                        __builtin_bit_cast(bf16x8, a),
                        __builtin_bit_cast(bf16x8, wf[nt][kk]), acc[nt], 0, 0, 0);
            }
#pragma unroll
            for (int nt = 0; nt < 8; ++nt)
#pragma unroll
                for (int r = 0; r < 4; ++r)
                    np[(size_t)(a0 + q * 4 + r) * 128 + nt * 16 + n] =
                        (u16)f2bf(acc[nt][r]);
        }
    } else {
        u32x4 waf[4];
#pragma unroll
        for (int kk = 0; kk < 4; ++kk) {
            u32x4 w;
#pragma unroll
            for (int jp = 0; jp < 4; ++jp) {
                const int k = kk * 32 + q * 8 + jp * 2;
                const float f0 = (n < 8) ? Wa[(size_t)k * 8 + n] : 0.f;
                const float f1 = (n < 8) ? Wa[(size_t)(k + 1) * 8 + n] : 0.f;
                w[jp] = pk2(f0, f1);
            }
            waf[kk] = w;
        }
        float b1v[8];
#pragma unroll
        for (int nt = 0; nt < 8; ++nt) b1v[nt] = b1[nt * 16 + n];
        const float bav = (n < 8) ? ba[n] : 0.f;

        const int n_tiles = n_agents >> 4;
        const int agent_blocks = gridDim.x - nbr_blocks;
        const int gw = (blockIdx.x - nbr_blocks) * 4 + wid;
        const int stride = agent_blocks * 4;
        for (int t = gw; t < n_tiles; t += stride) {
            const int a0 = t * 16;
#pragma unroll
            for (int it = 0; it < 4; ++it) {
                const int m = it * 4 + q;
                const float* bp = x_agent + (size_t)(a0 + m) * 128 + n * 8;
                const float4 v0 = *(const float4*)bp;
                const float4 v1 = *(const float4*)(bp + 4);
                u32x4 pkv;
                pkv[0] = pk2(v0.x, v0.y); pkv[1] = pk2(v0.z, v0.w);
                pkv[2] = pk2(v1.x, v1.y); pkv[3] = pk2(v1.z, v1.w);
                Abuf[wid].v[m * 17 + n] = pkv;
            }
            f32x4 acc[8];
#pragma unroll
            for (int nt = 0; nt < 8; ++nt) acc[nt] = zero;
            f32x4 acca = zero;
#pragma unroll
            for (int kk = 0; kk < 4; ++kk) {
                const u32x4 a = Abuf[wid].v[n * 17 + kk * 4 + q];
#pragma unroll
                for (int nt = 0; nt < 8; ++nt)
                    acc[nt] = __builtin_amdgcn_mfma_f32_16x16x32_bf16(
                        __builtin_bit_cast(bf16x8, a),
                        __builtin_bit_cast(bf16x8, wf[nt][kk]), acc[nt], 0, 0, 0);
                acca = __builtin_amdgcn_mfma_f32_16x16x32_bf16(
                    __builtin_bit_cast(bf16x8, a),
                    __builtin_bit_cast(bf16x8, waf[kk]), acca, 0, 0, 0);
            }
#pragma unroll
            for (int nt = 0; nt < 8; ++nt)
#pragma unroll
                for (int r = 0; r < 4; ++r)
                    ap[(size_t)(a0 + q * 4 + r) * 128 + nt * 16 + n] =
                        (u16)f2bf(acc[nt][r] + b1v[nt]);
            const float4 z = {0.f, 0.f, 0.f, 0.f};
#pragma unroll
            for (int it = 0; it < 4; ++it) {
                const int m = it * 4 + q;
                float4* zp = (float4*)(out + (size_t)(a0 + m) * 264 + 128 + n * 8);
                zp[0] = z; zp[1] = z;
            }
#pragma unroll
            for (int r = 0; r < 4; ++r) {
                const int m = q * 4 + r;
                if (n < 8) out[(size_t)(a0 + m) * 264 + 256 + n] = acca[r] + bav;
            }
        }
    }
}

// ---------------------------------------------------------------------------
// Edge kernel: ISA-level software pipeline. Compiler defeated source-level
// prefetch in R5/R6 (VGPR 56/76 prove the sets were sunk), so all gather
// loads + waits are inline asm with a hand-audited vmcnt ledger.
//   Per step: A=1 idx load, B=8 gathers (sc0: bypass L1, keep L2), 4 stores.
//   Steady state: both waits are exactly s_waitcnt vmcnt(13); prologue is
//   aligned (A0,A1,wait0,B0,A2,B1,wait(9),compute0) so the guarantee holds
//   from step 1. Exploits edge_slot[e]==e%16 (slot = lane&15 = MFMA row) and
//   lane-self src loads (lane l reads src[l&15] == its own MFMA A-row), so
//   there are no shuffles and no compiler vector loads in the loop.
// ---------------------------------------------------------------------------
struct GSet { u32x4 np[4]; u32x4 ap[4]; };

__device__ __forceinline__ void async_idx(const int* p, int& v) {
    asm volatile("global_load_dword %0, %1, off" : "=v"(v) : "v"(p) : "memory");
}
// one 256B row = 4 dwordx4 loads off one base (imm offsets), L1-bypass
__device__ __forceinline__ void async_row_sc0(const u16* base, u32x4 (&v)[4]) {
    asm volatile("global_load_dwordx4 %0, %4, off sc0\n\t"
                 "global_load_dwordx4 %1, %4, off offset:64 sc0\n\t"
                 "global_load_dwordx4 %2, %4, off offset:128 sc0\n\t"
                 "global_load_dwordx4 %3, %4, off offset:192 sc0"
                 : "=&v"(v[0]), "=&v"(v[1]), "=&v"(v[2]), "=&v"(v[3])
                 : "v"(base) : "memory");
}
#define TIE_SET(g) "+v"((g).np[0]), "+v"((g).np[1]), "+v"((g).np[2]), "+v"((g).np[3]), \
                   "+v"((g).ap[0]), "+v"((g).ap[1]), "+v"((g).ap[2]), "+v"((g).ap[3])

__device__ __forceinline__ void issue_gathers(const u16* __restrict__ np,
                                              const u16* __restrict__ ap,
                                              int src_self, int dst, int q, GSet& g)
{
    async_row_sc0(np + (size_t)(unsigned)src_self * 128 + q * 8, g.np);
    async_row_sc0(ap + (size_t)(unsigned)dst      * 128 + q * 8, g.ap);
}

__device__ __forceinline__ void compute_store(const GSet& g, int dst,
                                              const u32x4 (&w2f)[4], float b2v,
                                              float* __restrict__ out, int q, int n)
{
    f32x4 acc2 = {0.f, 0.f, 0.f, 0.f};
#pragma unroll
    for (int kk = 0; kk < 4; ++kk) {
        u32x4 hf;
#pragma unroll
        for (int j = 0; j < 4; ++j) {
            const u32 av = g.np[kk][j], bv = g.ap[kk][j];
            const float lo = fmaxf(bflo(av) + bflo(bv), 0.f);
            const float hi = fmaxf(bfhi(av) + bfhi(bv), 0.f);
            hf[j] = f2bf_fast(lo) | (f2bf_fast(hi) << 16);
        }
        acc2 = __builtin_amdgcn_mfma_f32_16x16x32_bf16(
            __builtin_bit_cast(bf16x8, hf),
            __builtin_bit_cast(bf16x8, w2f[kk]), acc2, 0, 0, 0);
    }
    float* orow = out + (size_t)dst * 264;
#pragma unroll
    for (int r = 0; r < 4; ++r)
        if (n < 8) orow[(q * 4 + r) * 8 + n] = acc2[r] + b2v;   // slot == row m
}

// PC = parity of the tile being computed; PF = 1-PC (tile being fetched)
template<int PC>
__device__ __forceinline__ void pipe_step(const u16* __restrict__ np,
                                          const u16* __restrict__ ap,
                                          const int* __restrict__ edge_src,
                                          const int* __restrict__ edge_dst,
                                          float* __restrict__ out,
                                          int t_c, int t_f, int t_a,
                                          int q, int n,
                                          int (&sreg)[2], GSet (&g)[2],
                                          const u32x4 (&w2f)[4], float b2v)
{
    constexpr int PF = 1 - PC;
    // A: src idx for tile t_a (overwrites sreg[PC]: its gathers issued last step)
    async_idx(edge_src + (size_t)t_a * 16 + n, sreg[PC]);
    // W1: src of tile t_f resident (13 newer ops: B(prev) 8 + D(prev) 4 + A 1)
    asm volatile("s_waitcnt vmcnt(13)" : "+v"(sreg[PF]) :: "memory");
    // B: gathers for tile t_f
    const int dst_f = edge_dst[(size_t)t_f * 16];   // uniform -> s_load (lgkm)
    issue_gathers(np, ap, sreg[PF], dst_f, q, g[PF]);
    // W2: gathers of tile t_c resident (13 newer: D(prev) 4 + A 1 + B 8)
    asm volatile("s_waitcnt vmcnt(13)" : TIE_SET(g[PC]) :: "memory");
    const int dst_c = edge_dst[(size_t)t_c * 16];
    compute_store(g[PC], dst_c, w2f, b2v, out, q, n);
}

__global__ __launch_bounds__(256, 3)
void edge_kernel(const u16* __restrict__ np, const u16* __restrict__ ap,
                 const float* __restrict__ W2, const float* __restrict__ b2,
                 const int* __restrict__ edge_src,
                 const int* __restrict__ edge_dst,
                 float* __restrict__ out, int n_tiles)
{
    const int wid = threadIdx.x >> 6;
    const int l   = threadIdx.x & 63;
    const int n   = l & 15;
    const int q   = l >> 4;

    u32x4 w2f[4];
#pragma unroll
    for (int kk = 0; kk < 4; ++kk) {
        u32x4 w;
#pragma unroll
        for (int jp = 0; jp < 4; ++jp) {
            const int k = kk * 32 + q * 8 + jp * 2;
            const float f0 = (n < 8) ? W2[(size_t)k * 8 + n] : 0.f;
            const float f1 = (n < 8) ? W2[(size_t)(k + 1) * 8 + n] : 0.f;
            w[jp] = pk2(f0, f1);
        }
        w2f[kk] = w;
    }
    const float b2v = (n < 8) ? b2[n] : 0.f;

    const int stride = gridDim.x * 4;
    const int gw = blockIdx.x * 4 + wid;
    if (gw >= n_tiles) return;
    const int nt_w = (n_tiles - gw + stride - 1) / stride;

    int t_c = gw;
    int t_f = (t_c + stride < n_tiles) ? t_c + stride : t_c;
    int t_a = (t_f + stride < n_tiles) ? t_f + stride : t_f;

    int sreg[2];
    GSet g[2];

    // ---- prologue: A0, A1, wait(0), B0, A2, B1, wait(9), compute0 ----
    async_idx(edge_src + (size_t)t_c * 16 + n, sreg[0]);
    async_idx(edge_src + (size_t)t_f * 16 + n, sreg[1]);
    asm volatile("s_waitcnt vmcnt(0)" : "+v"(sreg[0]), "+v"(sreg[1]) :: "memory");
    const int dst0 = edge_dst[(size_t)t_c * 16];
    issue_gathers(np, ap, sreg[0], dst0, q, g[0]);          // B0 (8)
    async_idx(edge_src + (size_t)t_a * 16 + n, sreg[0]);    // A2 (1) — sreg[0] free
    const int dst1 = edge_dst[(size_t)t_f * 16];
    issue_gathers(np, ap, sreg[1], dst1, q, g[1]);          // B1 (8)
    asm volatile("s_waitcnt vmcnt(9)" : TIE_SET(g[0]) :: "memory");  // B0 done
    compute_store(g[0], dst0, w2f, b2v, out, q, n);         // D0 (4)

    // ---- steady loop: tile i uses g[i&1]; src regs by same parity ----
    int i = 1;
    while (true) {
        if (i >= nt_w) break;
        t_c = t_f; t_f = t_a;
        t_a = (t_a + stride < n_tiles) ? t_a + stride : t_a;
        pipe_step<1>(np, ap, edge_src, edge_dst, out, t_c, t_f, t_a,
                     q, n, sreg, g, w2f, b2v);
        if (++i >= nt_w) break;
        t_c = t_f; t_f = t_a;
        t_a = (t_a + stride < n_tiles) ? t_a + stride : t_a;
        pipe_step<0>(np, ap, edge_src, edge_dst, out, t_c, t_f, t_a,
                     q, n, sreg, g, w2f, b2v);
        ++i;
    }
}

extern "C" void kernel_launch(void* const* d_in, const int* in_sizes, int n_in,
                              void* d_out, int out_size, void* d_ws, size_t ws_size,
                              hipStream_t stream)
{
    const float* x_nbr   = (const float*)d_in[0];
    const float* x_agent = (const float*)d_in[1];
    const float* W1      = (const float*)d_in[2];
    const float* b1      = (const float*)d_in[3];
    const float* W2      = (const float*)d_in[4];
    const float* b2      = (const float*)d_in[5];
    const float* Wa      = (const float*)d_in[6];
    const float* ba      = (const float*)d_in[7];
    const int* edge_src  = (const int*)d_in[8];
    const int* edge_dst  = (const int*)d_in[9];

    const int E        = in_sizes[8];
    const int n_nodes  = in_sizes[0] / 128;
    const int n_agents = in_sizes[1] / 128;
    const int n_tiles  = E / 16;

    u16* np = (u16*)d_ws;
    u16* ap = (u16*)d_ws + (size_t)n_nodes * 128;

    const int nbr_blocks = 512, agent_blocks = 512;
    precompute_kernel<<<dim3(nbr_blocks + agent_blocks), dim3(256), 0, stream>>>(
        x_nbr, x_agent, W1, b1, Wa, ba, np, ap, (float*)d_out,
        n_nodes, n_agents, nbr_blocks);
    // 768 blocks = 3 blocks/CU at launch_bounds(256,3); each wave >=16 tiles
    edge_kernel<<<dim3(768), dim3(256), 0, stream>>>(
        np, ap, W2, b2, edge_src, edge_dst, (float*)d_out, n_tiles);
}